// Round 9
// baseline (444.751 us; speedup 1.0000x reference)
//
#include <hip/hip_runtime.h>
#include <hip/hip_fp16.h>
#include <math.h>

#define N_NODES 50000
#define N_EDGES 800000
#define D 128
#define L 3
#define SLOPE 0.2f
#define LN_EPS 1e-5f
#define ETOT (N_EDGES + N_NODES)
#define SCAN_BLOCKS ((N_NODES + 1023) / 1024)   // 49

typedef _Float16 half8 __attribute__((ext_vector_type(8)));
typedef _Float16 h2v  __attribute__((ext_vector_type(2)));
typedef float f32x4 __attribute__((ext_vector_type(4)));

// ---------------- CSR build (once per call, reused for all layers) ----------

__global__ void rank_hist_kernel(const int* __restrict__ ei, int* __restrict__ counts,
                                 unsigned char* __restrict__ rank) {
    int idx = blockIdx.x * blockDim.x + threadIdx.x;
    if (idx >= ETOT) return;
    int d = (idx < N_EDGES) ? ei[N_EDGES + idx] : (idx - N_EDGES);
    rank[idx] = (unsigned char)atomicAdd(&counts[d], 1);
}

__global__ __launch_bounds__(1024) void scan1_kernel(const int* __restrict__ counts,
                                                     int* __restrict__ offsets,
                                                     int* __restrict__ bsum) {
    __shared__ int wsum[16];
    int tid = threadIdx.x;
    int lane = tid & 63, w = tid >> 6;
    int i = blockIdx.x * 1024 + tid;
    int v = (i < N_NODES) ? counts[i] : 0;
    int sc = v;
    #pragma unroll
    for (int off = 1; off < 64; off <<= 1) {
        int u = __shfl_up(sc, off);
        if (lane >= off) sc += u;
    }
    if (lane == 63) wsum[w] = sc;
    __syncthreads();
    if (w == 0) {
        int t2 = (lane < 16) ? wsum[lane] : 0;
        #pragma unroll
        for (int off = 1; off < 16; off <<= 1) {
            int u = __shfl_up(t2, off);
            if (lane >= off) t2 += u;
        }
        if (lane < 16) wsum[lane] = t2;
    }
    __syncthreads();
    int wpref = (w == 0) ? 0 : wsum[w - 1];
    if (i < N_NODES) offsets[i] = wpref + sc - v;      // block-local exclusive
    if (tid == 0) bsum[blockIdx.x] = wsum[15];
}

__global__ __launch_bounds__(64) void scan2_kernel(const int* __restrict__ bsum,
                                                   int* __restrict__ bpre) {
    int lane = threadIdx.x;
    int v = (lane < SCAN_BLOCKS) ? bsum[lane] : 0;
    int sc = v;
    #pragma unroll
    for (int off = 1; off < 64; off <<= 1) {
        int u = __shfl_up(sc, off);
        if (lane >= off) sc += u;
    }
    if (lane < SCAN_BLOCKS) bpre[lane] = sc - v;       // exclusive
}

__global__ __launch_bounds__(1024) void scan3_kernel(int* __restrict__ offsets,
                                                     const int* __restrict__ bpre) {
    int i = blockIdx.x * 1024 + threadIdx.x;
    if (i < N_NODES) offsets[i] += bpre[blockIdx.x];
    if (i == 0) offsets[N_NODES] = ETOT;
}

__global__ void scatter_kernel(const int* __restrict__ ei, const int* __restrict__ offsets,
                               const unsigned char* __restrict__ rank,
                               unsigned short* __restrict__ sorted16) {
    int idx = blockIdx.x * blockDim.x + threadIdx.x;
    if (idx >= ETOT) return;
    int s, d;
    if (idx < N_EDGES) { s = ei[idx]; d = ei[N_EDGES + idx]; }
    else               { s = d = idx - N_EDGES; }
    sorted16[offsets[d] + rank[idx]] = (unsigned short)s;   // no atomic
}

// ---------------- W -> fp16 MFMA B-frag + att fp16 (log2e-scaled) ----------

__global__ __launch_bounds__(256) void wfrag_kernel(const float* __restrict__ Wl,
                                                    const float* __restrict__ Wr,
                                                    const float* __restrict__ att,
                                                    _Float16* __restrict__ Wfrag,
                                                    _Float16* __restrict__ att16) {
    int u = blockIdx.x * 256 + threadIdx.x;   // 3*2*4*8*64 = 12288 slots
    if (u < 3 * D) att16[u] = (_Float16)(att[u] * 1.44269504f);
    if (u >= 3 * 4096) return;
    int lane = u & 63, nt = (u >> 6) & 7, kt = (u >> 9) & 3, y = (u >> 11) & 1, l = u >> 12;
    int r = lane & 15, q = lane >> 4;
    const float* W = (y ? Wr : Wl) + (size_t)l * D * D;
    half8 v;
    #pragma unroll
    for (int j = 0; j < 8; ++j)
        v[j] = (_Float16)W[(kt * 32 + q * 8 + j) * D + nt * 16 + r];
    *(half8*)&Wfrag[(size_t)u * 8] = v;
}

// ---------------- MFMA GEMM: xl,xr (fp16) = h @ {Wl,Wr} --------------------
// block = 4 waves; tile M=64, N=256 (both W in one block -> h staged ONCE).

__global__ __launch_bounds__(256) void gemm_mfma_kernel(
        const float* __restrict__ h, const _Float16* __restrict__ WfragL,
        _Float16* __restrict__ xlh, _Float16* __restrict__ xrh) {
    __shared__ half8 Afrag[1024];   // [mt][kt][lane], 16 KB
    int t = threadIdx.x;
    int row0 = blockIdx.x * 64;
    {
        int kt = t >> 6, q = (t >> 4) & 3, r = t & 15;
        int kc = kt * 4 + q;                  // 8-half chunk index
        #pragma unroll
        for (int i = 0; i < 4; ++i) {
            int row = row0 + i * 16 + r;
            float4 f0 = make_float4(0.f, 0.f, 0.f, 0.f), f1 = f0;
            if (row < N_NODES) {
                const float* p = &h[(size_t)row * D + kc * 8];
                f0 = *(const float4*)p;
                f1 = *(const float4*)(p + 4);
            }
            half8 v;
            v[0] = (_Float16)f0.x; v[1] = (_Float16)f0.y;
            v[2] = (_Float16)f0.z; v[3] = (_Float16)f0.w;
            v[4] = (_Float16)f1.x; v[5] = (_Float16)f1.y;
            v[6] = (_Float16)f1.z; v[7] = (_Float16)f1.w;
            Afrag[i * 256 + t] = v;           // linear lanes: conflict-floor
        }
    }
    __syncthreads();
    int w = t >> 6, lane = t & 63;
    f32x4 acc[16];
    #pragma unroll
    for (int i = 0; i < 16; ++i) acc[i] = (f32x4){0.f, 0.f, 0.f, 0.f};
    #pragma unroll
    for (int kt = 0; kt < 4; ++kt) {
        half8 a = Afrag[(w * 4 + kt) * 64 + lane];
        #pragma unroll
        for (int y = 0; y < 2; ++y) {
            #pragma unroll
            for (int nt = 0; nt < 8; ++nt) {
                half8 b = *(const half8*)&WfragL[(size_t)(((y * 4 + kt) * 8 + nt) * 64 + lane) * 8];
                acc[y * 8 + nt] = __builtin_amdgcn_mfma_f32_16x16x32_f16(a, b, acc[y * 8 + nt], 0, 0, 0);
            }
        }
    }
    int rq = lane >> 4, rc = lane & 15;
    int rbase = row0 + w * 16 + rq * 4;       // C/D: col=lane&15, row=(lane>>4)*4+reg
    #pragma unroll
    for (int y = 0; y < 2; ++y) {
        _Float16* out = y ? xrh : xlh;
        #pragma unroll
        for (int nt = 0; nt < 8; ++nt) {
            #pragma unroll
            for (int reg = 0; reg < 4; ++reg) {
                int row = rbase + reg;
                if (row < N_NODES)
                    out[(size_t)row * D + nt * 16 + rc] = (_Float16)acc[y * 8 + nt][reg];
            }
        }
    }
}

// ---------------- per-node GATv2 + softmax + LN + ELU + residual -----------
// one wave per node; lane = (e,h): e=lane&7 edge slot, h=lane>>3 head.
// Each lane computes the FULL head-h logit of its slot's edge via 8 chained
// v_dot2 (no DPP, 1 exp per 8 edges) and accumulates all 16 head channels in
// fp32. Cross-e reduction (DPP over lane bits 0..2) + mux once per node.
// Lane's output channels = h*16+2e = 2*lane -> epilogue identical to before.

__device__ __forceinline__ float ereduce8(float p) {
    int t;
    t = __builtin_amdgcn_update_dpp(0, __float_as_int(p), 0xB1, 0xF, 0xF, true);  // xor 1
    p += __int_as_float(t);
    t = __builtin_amdgcn_update_dpp(0, __float_as_int(p), 0x4E, 0xF, 0xF, true);  // xor 2
    p += __int_as_float(t);
    t = __builtin_amdgcn_update_dpp(0, __float_as_int(p), 0x141, 0xF, 0xF, true); // half-mirror
    p += __int_as_float(t);
    return p;
}

__device__ __forceinline__ h2v pair_of(half8 v, int i) {
    switch (i) {
        case 0: return __builtin_shufflevector(v, v, 0, 1);
        case 1: return __builtin_shufflevector(v, v, 2, 3);
        case 2: return __builtin_shufflevector(v, v, 4, 5);
        default: return __builtin_shufflevector(v, v, 6, 7);
    }
}

__global__ __launch_bounds__(256) void gat_node_kernel(
        const _Float16* __restrict__ xlh, const _Float16* __restrict__ xrh,
        const int* __restrict__ offsets, const unsigned short* __restrict__ sorted16,
        const _Float16* __restrict__ att16, const float* __restrict__ bias_l,
        const float* __restrict__ gamma_l, const float* __restrict__ beta_l,
        const float* __restrict__ hin, float* __restrict__ hout) {
    int node = (blockIdx.x * blockDim.x + threadIdx.x) >> 6;
    if (node >= N_NODES) return;
    int lane = threadIdx.x & 63;
    int e = lane & 7, h = lane >> 3;
    unsigned hoff = (unsigned)h * 32u;          // byte offset of head-h chunk
    // per-node constants: xr + att for head h (16 halves each)
    const char* xrb = (const char*)xrh + ((size_t)node << 8) + hoff;
    half8 xr0 = *(const half8*)xrb;
    half8 xr1 = *(const half8*)(xrb + 16);
    const char* atb = (const char*)att16 + hoff;
    half8 at0 = *(const half8*)atb;
    half8 at1 = *(const half8*)(atb + 16);
    h2v slope2; slope2[0] = (_Float16)SLOPE; slope2[1] = (_Float16)SLOPE;
    int beg = offsets[node], end = offsets[node + 1];
    float s = 0.f;
    float acc[16];
    #pragma unroll
    for (int c = 0; c < 16; ++c) acc[c] = 0.f;
    const char* xlb = (const char*)xlh;
    int e4 = e << 2;
    for (int c0 = beg; c0 < end; c0 += 64) {
        int cnt = end - c0; if (cnt > 64) cnt = 64;
        unsigned idxoff = (unsigned)sorted16[c0 + (lane < cnt ? lane : cnt - 1)] << 8;
        for (int j = 0; j < cnt; j += 8) {
            int slot = j + e;
            unsigned off = (unsigned)__builtin_amdgcn_ds_bpermute((j << 2) + e4, (int)idxoff);
            const char* p = xlb + (off + hoff);
            half8 v0 = *(const half8*)p;
            half8 v1 = *(const half8*)(p + 16);
            float pacc = 0.f;
            #pragma unroll
            for (int i = 0; i < 4; ++i) {
                h2v f = pair_of(v0, i) + pair_of(xr0, i);
                h2v lf = __builtin_elementwise_max(f, f * slope2);
                pacc = __builtin_amdgcn_fdot2(lf, pair_of(at0, i), pacc, false);
            }
            #pragma unroll
            for (int i = 0; i < 4; ++i) {
                h2v f = pair_of(v1, i) + pair_of(xr1, i);
                h2v lf = __builtin_elementwise_max(f, f * slope2);
                pacc = __builtin_amdgcn_fdot2(lf, pair_of(at1, i), pacc, false);
            }
            float ev = (slot < cnt) ? __builtin_amdgcn_exp2f(pacc) : 0.f;
            s += ev;
            #pragma unroll
            for (int i = 0; i < 4; ++i) {
                h2v a = pair_of(v0, i), b = pair_of(v1, i);
                acc[2 * i]     = fmaf(ev, (float)a[0], acc[2 * i]);
                acc[2 * i + 1] = fmaf(ev, (float)a[1], acc[2 * i + 1]);
                acc[8 + 2 * i]     = fmaf(ev, (float)b[0], acc[8 + 2 * i]);
                acc[8 + 2 * i + 1] = fmaf(ev, (float)b[1], acc[8 + 2 * i + 1]);
            }
        }
    }
    // reduce over e-lanes (bits 0..2): per-head denom + 16-channel sums
    s = ereduce8(s);
    #pragma unroll
    for (int c = 0; c < 16; ++c) acc[c] = ereduce8(acc[c]);
    // mux out this lane's 2 channels: elements 2e, 2e+1
    bool s2 = (e & 4) != 0, s1 = (e & 2) != 0, s0 = (e & 1) != 0;
    float m[8];
    #pragma unroll
    for (int c = 0; c < 8; ++c) m[c] = s2 ? acc[c + 8] : acc[c];
    float n[4];
    #pragma unroll
    for (int c = 0; c < 4; ++c) n[c] = s1 ? m[c + 4] : m[c];
    float a0 = s0 ? n[2] : n[0];
    float a1 = s0 ? n[3] : n[1];
    float inv = 1.f / s;                // every node has >=1 edge (self-loop)
    float2 bia = *(const float2*)&bias_l[2 * lane];
    float o0 = a0 * inv + bia.x;
    float o1 = a1 * inv + bia.y;
    float sum = o0 + o1, sq = o0 * o0 + o1 * o1;
    #pragma unroll
    for (int msk = 1; msk < 64; msk <<= 1) {
        sum += __shfl_xor(sum, msk);
        sq  += __shfl_xor(sq, msk);
    }
    float mu   = sum * (1.f / 128.f);
    float var  = sq * (1.f / 128.f) - mu * mu;
    float rstd = rsqrtf(var + LN_EPS);
    float2 gam = *(const float2*)&gamma_l[2 * lane];
    float2 bet = *(const float2*)&beta_l[2 * lane];
    float y0 = (o0 - mu) * rstd * gam.x + bet.x;
    float y1 = (o1 - mu) * rstd * gam.y + bet.y;
    y0 = y0 > 0.f ? y0 : __expf(y0) - 1.f;      // ELU (alpha=1)
    y1 = y1 > 0.f ? y1 : __expf(y1) - 1.f;
    size_t di = (size_t)node * D + 2 * lane;
    float2 hv = *(const float2*)&hin[di];
    hv.x += y0; hv.y += y1;
    *(float2*)&hout[di] = hv;
}

// ---------------------------------------------------------------------------

extern "C" void kernel_launch(void* const* d_in, const int* in_sizes, int n_in,
                              void* d_out, int out_size, void* d_ws, size_t ws_size,
                              hipStream_t stream) {
    const float* x     = (const float*)d_in[0];
    const float* Wl    = (const float*)d_in[1];
    const float* Wr    = (const float*)d_in[2];
    const float* att   = (const float*)d_in[3];
    const float* bias  = (const float*)d_in[4];
    const float* gamma = (const float*)d_in[5];
    const float* beta  = (const float*)d_in[6];
    const int*   ei    = (const int*)d_in[7];
    float* h = (float*)d_out;

    char* ws = (char*)d_ws;
    _Float16* xlh = (_Float16*)ws;   ws += (size_t)N_NODES * D * sizeof(_Float16);
    _Float16* xrh = (_Float16*)ws;   ws += (size_t)N_NODES * D * sizeof(_Float16);
    _Float16* Wfrag = (_Float16*)ws; ws += (size_t)3 * 4096 * 8 * sizeof(_Float16);
    _Float16* att16 = (_Float16*)ws; ws += (size_t)3 * D * sizeof(_Float16);
    int* offsets = (int*)ws;         ws += (size_t)(N_NODES + 4) * sizeof(int);
    int* counts  = (int*)ws;         ws += (size_t)N_NODES * sizeof(int);
    int* bsum    = (int*)ws;         ws += 64 * sizeof(int);
    int* bpre    = (int*)ws;         ws += 64 * sizeof(int);
    unsigned char* rank = (unsigned char*)ws;  ws += (size_t)ETOT;
    unsigned short* sorted16 = (unsigned short*)ws;   // ETOT u16

    // W fragments + att16 (all layers) + CSR by dst (shared by all 3 layers)
    wfrag_kernel<<<48, 256, 0, stream>>>(Wl, Wr, att, Wfrag, att16);
    (void)hipMemsetAsync(counts, 0, (size_t)N_NODES * sizeof(int), stream);
    rank_hist_kernel<<<(ETOT + 255) / 256, 256, 0, stream>>>(ei, counts, rank);
    scan1_kernel<<<SCAN_BLOCKS, 1024, 0, stream>>>(counts, offsets, bsum);
    scan2_kernel<<<1, 64, 0, stream>>>(bsum, bpre);
    scan3_kernel<<<SCAN_BLOCKS, 1024, 0, stream>>>(offsets, bpre);
    scatter_kernel<<<(ETOT + 255) / 256, 256, 0, stream>>>(ei, offsets, rank, sorted16);

    for (int l = 0; l < L; ++l) {
        const float* hin = (l == 0) ? x : h;
        gemm_mfma_kernel<<<(N_NODES + 63) / 64, 256, 0, stream>>>(
            hin, Wfrag + (size_t)l * 4096 * 8, xlh, xrh);
        gat_node_kernel<<<(N_NODES * 64 + 255) / 256, 256, 0, stream>>>(
            xlh, xrh, offsets, sorted16,
            att16 + (size_t)l * D, bias + (size_t)l * D,
            gamma + (size_t)l * D, beta + (size_t)l * D, hin, h);
    }
}

// Round 10
// 344.480 us; speedup vs baseline: 1.2911x; 1.2911x over previous
//
#include <hip/hip_runtime.h>
#include <hip/hip_fp16.h>
#include <math.h>

#define N_NODES 50000
#define N_EDGES 800000
#define D 128
#define L 3
#define SLOPE 0.2f
#define LN_EPS 1e-5f
#define ETOT (N_EDGES + N_NODES)
#define SCAN_BLOCKS ((N_NODES + 1023) / 1024)   // 49
#define DPC ((N_NODES + 7) / 8)                 // 6250 dsts per XCD class

typedef _Float16 half8 __attribute__((ext_vector_type(8)));
typedef _Float16 h2v  __attribute__((ext_vector_type(2)));
typedef float f32x4 __attribute__((ext_vector_type(4)));

// ---------------- CSR build (once per call, reused for all layers) ----------
// hist pass records each edge's rank within its dst (atomic returns old,
// max degree ~46 << 256 so u8 is safe), making placement atomic-free.

__global__ void rank_hist_kernel(const int* __restrict__ ei, int* __restrict__ counts,
                                 unsigned char* __restrict__ rank) {
    int idx = blockIdx.x * blockDim.x + threadIdx.x;
    if (idx >= ETOT) return;
    int d = (idx < N_EDGES) ? ei[N_EDGES + idx] : (idx - N_EDGES);
    rank[idx] = (unsigned char)atomicAdd(&counts[d], 1);
}

__global__ __launch_bounds__(1024) void scan1_kernel(const int* __restrict__ counts,
                                                     int* __restrict__ offsets,
                                                     int* __restrict__ bsum) {
    __shared__ int wsum[16];
    int tid = threadIdx.x;
    int lane = tid & 63, w = tid >> 6;
    int i = blockIdx.x * 1024 + tid;
    int v = (i < N_NODES) ? counts[i] : 0;
    int sc = v;
    #pragma unroll
    for (int off = 1; off < 64; off <<= 1) {
        int u = __shfl_up(sc, off);
        if (lane >= off) sc += u;
    }
    if (lane == 63) wsum[w] = sc;
    __syncthreads();
    if (w == 0) {
        int t2 = (lane < 16) ? wsum[lane] : 0;
        #pragma unroll
        for (int off = 1; off < 16; off <<= 1) {
            int u = __shfl_up(t2, off);
            if (lane >= off) t2 += u;
        }
        if (lane < 16) wsum[lane] = t2;
    }
    __syncthreads();
    int wpref = (w == 0) ? 0 : wsum[w - 1];
    if (i < N_NODES) offsets[i] = wpref + sc - v;      // block-local exclusive
    if (tid == 0) bsum[blockIdx.x] = wsum[15];
}

__global__ __launch_bounds__(64) void scan2_kernel(const int* __restrict__ bsum,
                                                   int* __restrict__ bpre) {
    int lane = threadIdx.x;
    int v = (lane < SCAN_BLOCKS) ? bsum[lane] : 0;
    int sc = v;
    #pragma unroll
    for (int off = 1; off < 64; off <<= 1) {
        int u = __shfl_up(sc, off);
        if (lane >= off) sc += u;
    }
    if (lane < SCAN_BLOCKS) bpre[lane] = sc - v;       // exclusive
}

__global__ __launch_bounds__(1024) void scan3_kernel(int* __restrict__ offsets,
                                                     const int* __restrict__ bpre) {
    int i = blockIdx.x * 1024 + threadIdx.x;
    if (i < N_NODES) offsets[i] += bpre[blockIdx.x];
    if (i == 0) offsets[N_NODES] = ETOT;
}

// XCD-partitioned scatter: block class p = blockIdx&7 writes only dsts in
// [p*DPC,(p+1)*DPC). With round-robin block->XCD dispatch each output region
// is written from one XCD only -> no cross-XCD line ping-pong. 8x coalesced
// re-reads of ei/rank are L3-served. Correct under ANY block->XCD mapping.

__global__ void scatter_kernel(const int* __restrict__ ei, const int* __restrict__ offsets,
                               const unsigned char* __restrict__ rank,
                               unsigned short* __restrict__ sorted16) {
    int cls = blockIdx.x & 7;
    int idx = (blockIdx.x >> 3) * blockDim.x + threadIdx.x;
    if (idx >= ETOT) return;
    int s, d;
    if (idx < N_EDGES) { s = ei[idx]; d = ei[N_EDGES + idx]; }
    else               { s = d = idx - N_EDGES; }
    if ((unsigned)(d - cls * DPC) >= (unsigned)DPC) return;
    sorted16[offsets[d] + rank[idx]] = (unsigned short)s;   // no atomic
}

// ---------------- W -> fp16 MFMA B-fragment precompute ---------------------
// Wfrag[l][y][kt][nt][lane][j]; element = W[kt*32+(lane>>4)*8+j][nt*16+(lane&15)]

__global__ __launch_bounds__(256) void wfrag_kernel(const float* __restrict__ Wl,
                                                    const float* __restrict__ Wr,
                                                    _Float16* __restrict__ Wfrag) {
    int u = blockIdx.x * 256 + threadIdx.x;   // 3*2*4*8*64 = 12288 slots
    if (u >= 3 * 4096) return;
    int lane = u & 63, nt = (u >> 6) & 7, kt = (u >> 9) & 3, y = (u >> 11) & 1, l = u >> 12;
    int r = lane & 15, q = lane >> 4;
    const float* W = (y ? Wr : Wl) + (size_t)l * D * D;
    half8 v;
    #pragma unroll
    for (int j = 0; j < 8; ++j)
        v[j] = (_Float16)W[(kt * 32 + q * 8 + j) * D + nt * 16 + r];
    *(half8*)&Wfrag[(size_t)u * 8] = v;
}

// ---------------- MFMA GEMM: xl,xr (fp16) = h @ {Wl,Wr} --------------------
// block = 4 waves; tile M=64, N=256 (both W in one block -> h staged ONCE).

__global__ __launch_bounds__(256) void gemm_mfma_kernel(
        const float* __restrict__ h, const _Float16* __restrict__ WfragL,
        _Float16* __restrict__ xlh, _Float16* __restrict__ xrh) {
    __shared__ half8 Afrag[1024];   // [mt][kt][lane], 16 KB
    int t = threadIdx.x;
    int row0 = blockIdx.x * 64;
    {
        int kt = t >> 6, q = (t >> 4) & 3, r = t & 15;
        int kc = kt * 4 + q;                  // 8-half chunk index
        #pragma unroll
        for (int i = 0; i < 4; ++i) {
            int row = row0 + i * 16 + r;
            float4 f0 = make_float4(0.f, 0.f, 0.f, 0.f), f1 = f0;
            if (row < N_NODES) {
                const float* p = &h[(size_t)row * D + kc * 8];
                f0 = *(const float4*)p;
                f1 = *(const float4*)(p + 4);
            }
            half8 v;
            v[0] = (_Float16)f0.x; v[1] = (_Float16)f0.y;
            v[2] = (_Float16)f0.z; v[3] = (_Float16)f0.w;
            v[4] = (_Float16)f1.x; v[5] = (_Float16)f1.y;
            v[6] = (_Float16)f1.z; v[7] = (_Float16)f1.w;
            Afrag[i * 256 + t] = v;           // linear lanes: conflict-floor
        }
    }
    __syncthreads();
    int w = t >> 6, lane = t & 63;
    f32x4 acc[16];
    #pragma unroll
    for (int i = 0; i < 16; ++i) acc[i] = (f32x4){0.f, 0.f, 0.f, 0.f};
    #pragma unroll
    for (int kt = 0; kt < 4; ++kt) {
        half8 a = Afrag[(w * 4 + kt) * 64 + lane];
        #pragma unroll
        for (int y = 0; y < 2; ++y) {
            #pragma unroll
            for (int nt = 0; nt < 8; ++nt) {
                half8 b = *(const half8*)&WfragL[(size_t)(((y * 4 + kt) * 8 + nt) * 64 + lane) * 8];
                acc[y * 8 + nt] = __builtin_amdgcn_mfma_f32_16x16x32_f16(a, b, acc[y * 8 + nt], 0, 0, 0);
            }
        }
    }
    int rq = lane >> 4, rc = lane & 15;
    int rbase = row0 + w * 16 + rq * 4;       // C/D: col=lane&15, row=(lane>>4)*4+reg
    #pragma unroll
    for (int y = 0; y < 2; ++y) {
        _Float16* out = y ? xrh : xlh;
        #pragma unroll
        for (int nt = 0; nt < 8; ++nt) {
            #pragma unroll
            for (int reg = 0; reg < 4; ++reg) {
                int row = rbase + reg;
                if (row < N_NODES)
                    out[(size_t)row * D + nt * 16 + rc] = (_Float16)acc[y * 8 + nt][reg];
            }
        }
    }
}

// ---------------- per-node GATv2 + softmax + LN + ELU + residual -----------
// one wave per node; lane holds channels {2*lane, 2*lane+1}; head = lane>>3.
// (R7 structure: 8-deep edge blocks + fine serial remainder — proven 48 us.)
// Packed-fp16 logits; exp2 with log2e folded into att. DPP head reduction.

__device__ __forceinline__ float head_reduce8(float p) {
    int t;
    t = __builtin_amdgcn_update_dpp(0, __float_as_int(p), 0xB1, 0xF, 0xF, true);  // xor 1
    p += __int_as_float(t);
    t = __builtin_amdgcn_update_dpp(0, __float_as_int(p), 0x4E, 0xF, 0xF, true);  // xor 2
    p += __int_as_float(t);
    t = __builtin_amdgcn_update_dpp(0, __float_as_int(p), 0x141, 0xF, 0xF, true); // half-mirror
    p += __int_as_float(t);
    return p;
}

__device__ __forceinline__ float logit2(h2v v, h2v xrv2, h2v att2, h2v slope2) {
    h2v f  = v + xrv2;                                   // v_pk_add_f16
    h2v lf = __builtin_elementwise_max(f, f * slope2);   // v_pk_max/mul_f16
    return __builtin_amdgcn_fdot2(lf, att2, 0.f, false); // v_dot2_f32_f16
}

__device__ __forceinline__ float2 h2f(h2v v) {
    return make_float2((float)v[0], (float)v[1]);
}

__global__ __launch_bounds__(256) void gat_node_kernel(
        const _Float16* __restrict__ xlh, const _Float16* __restrict__ xrh,
        const int* __restrict__ offsets, const unsigned short* __restrict__ sorted16,
        const float* __restrict__ att_l, const float* __restrict__ bias_l,
        const float* __restrict__ gamma_l, const float* __restrict__ beta_l,
        const float* __restrict__ hin, float* __restrict__ hout) {
    int node = (blockIdx.x * blockDim.x + threadIdx.x) >> 6;
    if (node >= N_NODES) return;
    int lane = threadIdx.x & 63;
    unsigned laneoff = lane * 4u;               // byte offset of this lane's half2
    h2v xrv2 = ((const h2v*)xrh)[(size_t)node * 64 + lane];
    float2 attf = *(const float2*)&att_l[2 * lane];
    h2v att2;
    att2[0] = (_Float16)(attf.x * 1.44269504f);
    att2[1] = (_Float16)(attf.y * 1.44269504f);
    h2v slope2;
    slope2[0] = (_Float16)SLOPE;
    slope2[1] = (_Float16)SLOPE;
    int beg = offsets[node], end = offsets[node + 1];
    float s = 0.f, accx = 0.f, accy = 0.f;
    const char* xlb = (const char*)xlh;
    for (int c0 = beg; c0 < end; c0 += 64) {
        int cnt = end - c0; if (cnt > 64) cnt = 64;
        unsigned idx = sorted16[c0 + (lane < cnt ? lane : cnt - 1)];   // coalesced u16
        unsigned off = idx << 8;                 // byte offset of fp16 row (128*2B)
        int j = 0;
        for (; j + 8 <= cnt; j += 8) {
            unsigned o0 = __builtin_amdgcn_readlane(off, j)     + laneoff;
            unsigned o1 = __builtin_amdgcn_readlane(off, j + 1) + laneoff;
            unsigned o2 = __builtin_amdgcn_readlane(off, j + 2) + laneoff;
            unsigned o3 = __builtin_amdgcn_readlane(off, j + 3) + laneoff;
            unsigned o4 = __builtin_amdgcn_readlane(off, j + 4) + laneoff;
            unsigned o5 = __builtin_amdgcn_readlane(off, j + 5) + laneoff;
            unsigned o6 = __builtin_amdgcn_readlane(off, j + 6) + laneoff;
            unsigned o7 = __builtin_amdgcn_readlane(off, j + 7) + laneoff;
            h2v v0 = *(const h2v*)(xlb + o0);
            h2v v1 = *(const h2v*)(xlb + o1);
            h2v v2 = *(const h2v*)(xlb + o2);
            h2v v3 = *(const h2v*)(xlb + o3);
            h2v v4 = *(const h2v*)(xlb + o4);
            h2v v5 = *(const h2v*)(xlb + o5);
            h2v v6 = *(const h2v*)(xlb + o6);
            h2v v7 = *(const h2v*)(xlb + o7);
            float p0 = logit2(v0, xrv2, att2, slope2);
            float p1 = logit2(v1, xrv2, att2, slope2);
            float p2 = logit2(v2, xrv2, att2, slope2);
            float p3 = logit2(v3, xrv2, att2, slope2);
            float p4 = logit2(v4, xrv2, att2, slope2);
            float p5 = logit2(v5, xrv2, att2, slope2);
            float p6 = logit2(v6, xrv2, att2, slope2);
            float p7 = logit2(v7, xrv2, att2, slope2);
            p0 = head_reduce8(p0); p1 = head_reduce8(p1);
            p2 = head_reduce8(p2); p3 = head_reduce8(p3);
            p4 = head_reduce8(p4); p5 = head_reduce8(p5);
            p6 = head_reduce8(p6); p7 = head_reduce8(p7);
            float e0 = __builtin_amdgcn_exp2f(p0), e1 = __builtin_amdgcn_exp2f(p1);
            float e2 = __builtin_amdgcn_exp2f(p2), e3 = __builtin_amdgcn_exp2f(p3);
            float e4 = __builtin_amdgcn_exp2f(p4), e5 = __builtin_amdgcn_exp2f(p5);
            float e6 = __builtin_amdgcn_exp2f(p6), e7 = __builtin_amdgcn_exp2f(p7);
            s += ((e0 + e1) + (e2 + e3)) + ((e4 + e5) + (e6 + e7));
            float2 f0 = h2f(v0), f1 = h2f(v1);
            float2 f2 = h2f(v2), f3 = h2f(v3);
            float2 f4 = h2f(v4), f5 = h2f(v5);
            float2 f6 = h2f(v6), f7 = h2f(v7);
            accx = fmaf(e0, f0.x, accx); accy = fmaf(e0, f0.y, accy);
            accx = fmaf(e1, f1.x, accx); accy = fmaf(e1, f1.y, accy);
            accx = fmaf(e2, f2.x, accx); accy = fmaf(e2, f2.y, accy);
            accx = fmaf(e3, f3.x, accx); accy = fmaf(e3, f3.y, accy);
            accx = fmaf(e4, f4.x, accx); accy = fmaf(e4, f4.y, accy);
            accx = fmaf(e5, f5.x, accx); accy = fmaf(e5, f5.y, accy);
            accx = fmaf(e6, f6.x, accx); accy = fmaf(e6, f6.y, accy);
            accx = fmaf(e7, f7.x, accx); accy = fmaf(e7, f7.y, accy);
        }
        for (; j < cnt; ++j) {
            unsigned o0 = __builtin_amdgcn_readlane(off, j) + laneoff;
            h2v v0 = *(const h2v*)(xlb + o0);
            float p0 = logit2(v0, xrv2, att2, slope2);
            p0 = head_reduce8(p0);
            float e0 = __builtin_amdgcn_exp2f(p0);
            s += e0;
            float2 f0 = h2f(v0);
            accx = fmaf(e0, f0.x, accx);
            accy = fmaf(e0, f0.y, accy);
        }
    }
    float inv = 1.f / s;                // every node has >=1 edge (self-loop)
    float2 bia = *(const float2*)&bias_l[2 * lane];
    float o0 = accx * inv + bia.x;
    float o1 = accy * inv + bia.y;
    float sum = o0 + o1, sq = o0 * o0 + o1 * o1;
    #pragma unroll
    for (int msk = 1; msk < 64; msk <<= 1) {
        sum += __shfl_xor(sum, msk);
        sq  += __shfl_xor(sq, msk);
    }
    float mu   = sum * (1.f / 128.f);
    float var  = sq * (1.f / 128.f) - mu * mu;
    float rstd = rsqrtf(var + LN_EPS);
    float2 gam = *(const float2*)&gamma_l[2 * lane];
    float2 bet = *(const float2*)&beta_l[2 * lane];
    float y0 = (o0 - mu) * rstd * gam.x + bet.x;
    float y1 = (o1 - mu) * rstd * gam.y + bet.y;
    y0 = y0 > 0.f ? y0 : __expf(y0) - 1.f;      // ELU (alpha=1)
    y1 = y1 > 0.f ? y1 : __expf(y1) - 1.f;
    size_t di = (size_t)node * D + 2 * lane;
    float2 hv = *(const float2*)&hin[di];
    hv.x += y0; hv.y += y1;
    *(float2*)&hout[di] = hv;
}

// ---------------------------------------------------------------------------

extern "C" void kernel_launch(void* const* d_in, const int* in_sizes, int n_in,
                              void* d_out, int out_size, void* d_ws, size_t ws_size,
                              hipStream_t stream) {
    const float* x     = (const float*)d_in[0];
    const float* Wl    = (const float*)d_in[1];
    const float* Wr    = (const float*)d_in[2];
    const float* att   = (const float*)d_in[3];
    const float* bias  = (const float*)d_in[4];
    const float* gamma = (const float*)d_in[5];
    const float* beta  = (const float*)d_in[6];
    const int*   ei    = (const int*)d_in[7];
    float* h = (float*)d_out;

    char* ws = (char*)d_ws;
    _Float16* xlh = (_Float16*)ws;   ws += (size_t)N_NODES * D * sizeof(_Float16);
    _Float16* xrh = (_Float16*)ws;   ws += (size_t)N_NODES * D * sizeof(_Float16);
    _Float16* Wfrag = (_Float16*)ws; ws += (size_t)3 * 4096 * 8 * sizeof(_Float16);
    int* offsets = (int*)ws;         ws += (size_t)(N_NODES + 4) * sizeof(int);
    int* counts  = (int*)ws;         ws += (size_t)N_NODES * sizeof(int);
    int* bsum    = (int*)ws;         ws += 64 * sizeof(int);
    int* bpre    = (int*)ws;         ws += 64 * sizeof(int);
    unsigned char* rank = (unsigned char*)ws;  ws += (size_t)ETOT;
    unsigned short* sorted16 = (unsigned short*)ws;   // ETOT u16

    // W fragments (all layers) + CSR by dst (shared by all 3 layers)
    wfrag_kernel<<<48, 256, 0, stream>>>(Wl, Wr, Wfrag);
    (void)hipMemsetAsync(counts, 0, (size_t)N_NODES * sizeof(int), stream);
    rank_hist_kernel<<<(ETOT + 255) / 256, 256, 0, stream>>>(ei, counts, rank);
    scan1_kernel<<<SCAN_BLOCKS, 1024, 0, stream>>>(counts, offsets, bsum);
    scan2_kernel<<<1, 64, 0, stream>>>(bsum, bpre);
    scan3_kernel<<<SCAN_BLOCKS, 1024, 0, stream>>>(offsets, bpre);
    scatter_kernel<<<8 * ((ETOT + 255) / 256), 256, 0, stream>>>(ei, offsets, rank, sorted16);

    for (int l = 0; l < L; ++l) {
        const float* hin = (l == 0) ? x : h;
        gemm_mfma_kernel<<<(N_NODES + 63) / 64, 256, 0, stream>>>(
            hin, Wfrag + (size_t)l * 4096 * 8, xlh, xrh);
        gat_node_kernel<<<(N_NODES * 64 + 255) / 256, 256, 0, stream>>>(
            xlh, xrh, offsets, sorted16,
            att + (size_t)l * D, bias + (size_t)l * D,
            gamma + (size_t)l * D, beta + (size_t)l * D, hin, h);
    }
}